// Round 1
// baseline (1756.445 us; speedup 1.0000x reference)
//
#include <hip/hip_runtime.h>
#include <hip/hip_bf16.h>

#define B_SEG 65536
#define N_NODES 1048576

__device__ __forceinline__ float lane_bcast(float v, int k) {
    return __uint_as_float(__builtin_amdgcn_readlane(__float_as_uint(v), k));
}

// ---------------- histogram: count nodes per segment (both eyes) ----------------
__global__ void histo_kernel(const int* __restrict__ idx0, const int* __restrict__ idx1,
                             int* __restrict__ cnt0, int* __restrict__ cnt1, int n) {
    int stride = gridDim.x * blockDim.x;
    for (int i = blockIdx.x * blockDim.x + threadIdx.x; i < 2 * n; i += stride) {
        if (i < n) atomicAdd(&cnt0[idx0[i]], 1);
        else       atomicAdd(&cnt1[idx1[i - n]], 1);
    }
}

// ---------------- exclusive scan over B counters (one block per eye) ----------------
// Also zeroes the counter array so fill_kernel can reuse it as a cursor.
__global__ __launch_bounds__(1024) void scan_kernel(int* cnt0, int* cnt1,
                                                    int* off0, int* off1) {
    __shared__ int lds[2][1024];
    int* cnt = (blockIdx.x == 0) ? cnt0 : cnt1;
    int* off = (blockIdx.x == 0) ? off0 : off1;
    int t = threadIdx.x;
    int carry = 0;
    for (int c = 0; c < B_SEG / 1024; ++c) {
        int i = c * 1024 + t;
        int v = cnt[i];
        lds[0][t] = v;
        __syncthreads();
        int p = 0;
        for (int d = 1; d < 1024; d <<= 1) {
            int a = lds[p][t];
            if (t >= d) a += lds[p][t - d];
            lds[1 - p][t] = a;
            __syncthreads();
            p ^= 1;
        }
        int incl  = lds[p][t];
        int total = lds[p][1023];
        off[i] = carry + incl - v;   // exclusive prefix
        cnt[i] = 0;                  // reset for cursor use
        carry += total;
        __syncthreads();             // protect lds before next chunk overwrites
    }
    if (t == 0) off[B_SEG] = carry;  // == N
}

// ---------------- fill CSR node-order arrays ----------------
__global__ void fill_kernel(const int* __restrict__ idx0, const int* __restrict__ idx1,
                            const int* __restrict__ off0, const int* __restrict__ off1,
                            int* __restrict__ cur0, int* __restrict__ cur1,
                            int* __restrict__ ord0, int* __restrict__ ord1, int n) {
    int stride = gridDim.x * blockDim.x;
    for (int i = blockIdx.x * blockDim.x + threadIdx.x; i < 2 * n; i += stride) {
        if (i < n) {
            int s = idx0[i];
            int p = atomicAdd(&cur0[s], 1);
            ord0[off0[s] + p] = i;
        } else {
            int s = idx1[i - n];
            int p = atomicAdd(&cur1[s], 1);
            ord1[off1[s] + p] = i - n;
        }
    }
}

// ---------------- per-segment mean of relu(x@Wr+br) ----------------
// One segment per wave, no barriers. Wr columns (lane, lane+64) in 128 VGPRs.
// x row broadcast via v_readlane (VALU pipe, avoids LDS pipe oversubscription).
#define SEGS_PER_WAVE 8
__global__ __launch_bounds__(256) void eye_means_kernel(
        const float* __restrict__ x, const float* __restrict__ Wr,
        const float* __restrict__ br, const int* __restrict__ off,
        const int* __restrict__ ord, float* __restrict__ means) {
    int lane = threadIdx.x & 63;
    int wid  = blockIdx.x * (blockDim.x >> 6) + (threadIdx.x >> 6);

    float w0[64], w1[64];
    #pragma unroll
    for (int k = 0; k < 64; ++k) {
        w0[k] = Wr[k * 128 + lane];
        w1[k] = Wr[k * 128 + 64 + lane];
    }
    float b0 = br[lane], b1 = br[64 + lane];

    int s_begin = wid * SEGS_PER_WAVE;
    for (int s = s_begin; s < s_begin + SEGS_PER_WAVE; ++s) {
        int base = off[s];
        int sz   = off[s + 1] - base;
        float acc0 = 0.f, acc1 = 0.f;
        if (sz > 0) {
            int n = ord[base];
            float xv = x[(size_t)n * 64 + lane];
            for (int i = 0; i < sz; ++i) {
                float xnext = 0.f;
                if (i + 1 < sz) {                       // prefetch next node's row
                    int n2 = ord[base + i + 1];
                    xnext = x[(size_t)n2 * 64 + lane];
                }
                float d0 = b0, d1 = b1;                  // two independent fma chains
                #pragma unroll
                for (int k = 0; k < 64; ++k) {
                    float xs = lane_bcast(xv, k);
                    d0 = fmaf(xs, w0[k], d0);
                    d1 = fmaf(xs, w1[k], d1);
                }
                acc0 += fmaxf(d0, 0.f);                  // relu BEFORE segment sum
                acc1 += fmaxf(d1, 0.f);
                xv = xnext;
            }
        }
        float inv = (sz > 0) ? 1.f / (float)sz : 0.f;
        means[(size_t)s * 128 + lane]      = acc0 * inv;
        means[(size_t)s * 128 + 64 + lane] = acc1 * inv;
    }
}

// ---------------- generic fp32 tiled GEMM: C = act(A[M,K] @ W[K,N] + bias) ----------------
// block tile 64x64, K-step 16, 256 threads, 4x4 micro-tile per thread.
template<int RELU>
__global__ __launch_bounds__(256) void gemm_kernel(
        const float* __restrict__ A, const float* __restrict__ W,
        const float* __restrict__ bias, float* __restrict__ C,
        int K, int ldc, int N) {
    __shared__ float As[16][68];   // [k][m], padded (+4) to kill store conflicts
    __shared__ float Ws[16][64];   // [k][n]
    int t  = threadIdx.x;
    int tx = t & 15, ty = t >> 4;
    int m0 = blockIdx.x * 64;
    int n0 = blockIdx.y * 64;

    float acc[4][4];
    #pragma unroll
    for (int j = 0; j < 4; ++j) {
        float bv = bias[n0 + tx * 4 + j];
        acc[0][j] = bv; acc[1][j] = bv; acc[2][j] = bv; acc[3][j] = bv;
    }

    int am = t >> 2, ak4 = t & 3;     // A staging: 64 rows x (4x float4 along k)
    int wk = t >> 4, wn4 = t & 15;    // W staging: 16 rows x (16x float4 along n)

    for (int k0 = 0; k0 < K; k0 += 16) {
        float4 av = *(const float4*)&A[(size_t)(m0 + am) * K + k0 + ak4 * 4];
        float4 wv = *(const float4*)&W[(size_t)(k0 + wk) * N + n0 + wn4 * 4];
        __syncthreads();
        As[ak4 * 4 + 0][am] = av.x;
        As[ak4 * 4 + 1][am] = av.y;
        As[ak4 * 4 + 2][am] = av.z;
        As[ak4 * 4 + 3][am] = av.w;
        *(float4*)&Ws[wk][wn4 * 4] = wv;
        __syncthreads();
        #pragma unroll
        for (int kk = 0; kk < 16; ++kk) {
            float4 a = *(const float4*)&As[kk][ty * 4];
            float4 w = *(const float4*)&Ws[kk][tx * 4];
            acc[0][0] = fmaf(a.x, w.x, acc[0][0]);
            acc[0][1] = fmaf(a.x, w.y, acc[0][1]);
            acc[0][2] = fmaf(a.x, w.z, acc[0][2]);
            acc[0][3] = fmaf(a.x, w.w, acc[0][3]);
            acc[1][0] = fmaf(a.y, w.x, acc[1][0]);
            acc[1][1] = fmaf(a.y, w.y, acc[1][1]);
            acc[1][2] = fmaf(a.y, w.z, acc[1][2]);
            acc[1][3] = fmaf(a.y, w.w, acc[1][3]);
            acc[2][0] = fmaf(a.z, w.x, acc[2][0]);
            acc[2][1] = fmaf(a.z, w.y, acc[2][1]);
            acc[2][2] = fmaf(a.z, w.z, acc[2][2]);
            acc[2][3] = fmaf(a.z, w.w, acc[2][3]);
            acc[3][0] = fmaf(a.w, w.x, acc[3][0]);
            acc[3][1] = fmaf(a.w, w.y, acc[3][1]);
            acc[3][2] = fmaf(a.w, w.z, acc[3][2]);
            acc[3][3] = fmaf(a.w, w.w, acc[3][3]);
        }
    }

    #pragma unroll
    for (int i = 0; i < 4; ++i) {
        float4 o;
        o.x = RELU ? fmaxf(acc[i][0], 0.f) : acc[i][0];
        o.y = RELU ? fmaxf(acc[i][1], 0.f) : acc[i][1];
        o.z = RELU ? fmaxf(acc[i][2], 0.f) : acc[i][2];
        o.w = RELU ? fmaxf(acc[i][3], 0.f) : acc[i][3];
        *(float4*)&C[(size_t)(m0 + ty * 4 + i) * ldc + n0 + tx * 4] = o;
    }
}

extern "C" void kernel_launch(void* const* d_in, const int* in_sizes, int n_in,
                              void* d_out, int out_size, void* d_ws, size_t ws_size,
                              hipStream_t stream) {
    const float* x0  = (const float*)d_in[0];
    const float* x1  = (const float*)d_in[1];
    const int*   idx0 = (const int*)d_in[2];
    const int*   idx1 = (const int*)d_in[3];
    const float* Wr0 = (const float*)d_in[4];
    const float* br0 = (const float*)d_in[5];
    const float* Wc0 = (const float*)d_in[6];
    const float* bc0 = (const float*)d_in[7];
    const float* Wr1 = (const float*)d_in[8];
    const float* br1 = (const float*)d_in[9];
    const float* Wc1 = (const float*)d_in[10];
    const float* bc1 = (const float*)d_in[11];
    const float* Wb1 = (const float*)d_in[12];
    const float* bb1 = (const float*)d_in[13];
    const float* Wb2 = (const float*)d_in[14];
    const float* bb2 = (const float*)d_in[15];
    float* out = (float*)d_out;

    const int N = N_NODES;
    char* w = (char*)d_ws;
    auto alloc = [&](size_t bytes) { void* p = (void*)w; w += (bytes + 255) & ~(size_t)255; return p; };
    int* cnt0 = (int*)alloc((size_t)B_SEG * 4);          // also cursor (contiguous with cnt1)
    int* cnt1 = (int*)alloc((size_t)B_SEG * 4);
    int* off0 = (int*)alloc((size_t)(B_SEG + 1) * 4);
    int* off1 = (int*)alloc((size_t)(B_SEG + 1) * 4);
    int* ord0 = (int*)alloc((size_t)N * 4);
    int* ord1 = (int*)alloc((size_t)N * 4);
    float* means0 = (float*)alloc((size_t)B_SEG * 128 * 4);
    float* means1 = (float*)alloc((size_t)B_SEG * 128 * 4);  // contiguous after means0
    float* z      = (float*)alloc((size_t)B_SEG * 256 * 4);
    float* hb     = means0;   // reuse means region (67MB) as brain hidden buffer

    hipMemsetAsync(cnt0, 0, 2 * (size_t)B_SEG * sizeof(int), stream);
    histo_kernel<<<2048, 256, 0, stream>>>(idx0, idx1, cnt0, cnt1, N);
    scan_kernel<<<2, 1024, 0, stream>>>(cnt0, cnt1, off0, off1);
    fill_kernel<<<2048, 256, 0, stream>>>(idx0, idx1, off0, off1, cnt0, cnt1, ord0, ord1, N);

    // 2048 blocks * 4 waves * 8 segs = 65536 segments, exact cover
    eye_means_kernel<<<2048, 256, 0, stream>>>(x0, Wr0, br0, off0, ord0, means0);
    eye_means_kernel<<<2048, 256, 0, stream>>>(x1, Wr1, br1, off1, ord1, means1);

    // e0/e1 = relu(mean @ Wc + bc) -> z[:, 0:128] / z[:, 128:256]
    gemm_kernel<1><<<dim3(1024, 2), 256, 0, stream>>>(means0, Wc0, bc0, z,       128, 256, 128);
    gemm_kernel<1><<<dim3(1024, 2), 256, 0, stream>>>(means1, Wc1, bc1, z + 128, 128, 256, 128);
    // h = relu(z @ Wb1 + bb1)
    gemm_kernel<1><<<dim3(1024, 4), 256, 0, stream>>>(z,  Wb1, bb1, hb,  256, 256, 256);
    // out = h @ Wb2 + bb2
    gemm_kernel<0><<<dim3(1024, 2), 256, 0, stream>>>(hb, Wb2, bb2, out, 256, 128, 128);
}

// Round 2
// 757.039 us; speedup vs baseline: 2.3202x; 2.3202x over previous
//
#include <hip/hip_runtime.h>
#include <hip/hip_bf16.h>

#define B_SEG 65536
#define N_NODES 1048576

typedef __attribute__((ext_vector_type(8))) short bf16x8;
typedef __attribute__((ext_vector_type(4))) float f32x4;

__device__ __forceinline__ short f2bf(float f) {
    unsigned u = __float_as_uint(f);
    unsigned r = (u + 0x7FFFu + ((u >> 16) & 1u)) >> 16;   // round-to-nearest-even
    return (short)r;
}

// ---------------- histogram: count nodes per segment (both eyes) ----------------
__global__ void histo_kernel(const int* __restrict__ idx0, const int* __restrict__ idx1,
                             int* __restrict__ cnt0, int* __restrict__ cnt1, int n) {
    int stride = gridDim.x * blockDim.x;
    for (int i = blockIdx.x * blockDim.x + threadIdx.x; i < 2 * n; i += stride) {
        if (i < n) atomicAdd(&cnt0[idx0[i]], 1);
        else       atomicAdd(&cnt1[idx1[i - n]], 1);
    }
}

// ---------------- exclusive scan over B counters (one block per eye) ----------------
__global__ __launch_bounds__(1024) void scan_kernel(int* cnt0, int* cnt1,
                                                    int* off0, int* off1) {
    __shared__ int lds[2][1024];
    int* cnt = (blockIdx.x == 0) ? cnt0 : cnt1;
    int* off = (blockIdx.x == 0) ? off0 : off1;
    int t = threadIdx.x;
    int carry = 0;
    for (int c = 0; c < B_SEG / 1024; ++c) {
        int i = c * 1024 + t;
        int v = cnt[i];
        lds[0][t] = v;
        __syncthreads();
        int p = 0;
        for (int d = 1; d < 1024; d <<= 1) {
            int a = lds[p][t];
            if (t >= d) a += lds[p][t - d];
            lds[1 - p][t] = a;
            __syncthreads();
            p ^= 1;
        }
        int incl  = lds[p][t];
        int total = lds[p][1023];
        off[i] = carry + incl - v;   // exclusive prefix
        cnt[i] = 0;                  // reset for cursor use
        carry += total;
        __syncthreads();
    }
    if (t == 0) off[B_SEG] = carry;  // == N
}

// ---------------- fill CSR node-order arrays ----------------
__global__ void fill_kernel(const int* __restrict__ idx0, const int* __restrict__ idx1,
                            const int* __restrict__ off0, const int* __restrict__ off1,
                            int* __restrict__ cur0, int* __restrict__ cur1,
                            int* __restrict__ ord0, int* __restrict__ ord1, int n) {
    int stride = gridDim.x * blockDim.x;
    for (int i = blockIdx.x * blockDim.x + threadIdx.x; i < 2 * n; i += stride) {
        if (i < n) {
            int s = idx0[i];
            int p = atomicAdd(&cur0[s], 1);
            ord0[off0[s] + p] = i;
        } else {
            int s = idx1[i - n];
            int p = atomicAdd(&cur1[s], 1);
            ord1[off1[s] + p] = i - n;
        }
    }
}

// ---------------- per-segment mean of relu(x@Wr+br), MFMA version ----------------
// One segment per wave. Batches of 16 CSR rows = M of mfma_f32_16x16x32_bf16.
// B (Wr) fragments live in 64 VGPRs; A gathered+converted per batch.
// C layout: col = lane&15, row = (lane>>4)*4 + reg  [verified, learn_hip m89/m91]
// A: row = lane&15, k = (lane>>4)*8 + j ; B: col = lane&15, k = (lane>>4)*8 + j
#define SEGS_PER_WAVE 8
__global__ __launch_bounds__(256, 3) void eye_means_mfma(
        const float* __restrict__ x, const float* __restrict__ Wr,
        const float* __restrict__ br, const int* __restrict__ off,
        const int* __restrict__ ord, float* __restrict__ means) {
    int lane = threadIdx.x & 63;
    int wid  = blockIdx.x * (blockDim.x >> 6) + (threadIdx.x >> 6);
    int c  = lane & 15;    // A row / B-C col within group
    int kq = lane >> 4;    // k-quarter (8-wide chunk selector)

    // preload B fragments: bfr[g][h] covers cols g*16..+15, k = h*32 + kq*8 .. +7
    bf16x8 bfr[8][2];
    float rbias[8];
    #pragma unroll
    for (int g = 0; g < 8; ++g) {
        #pragma unroll
        for (int h = 0; h < 2; ++h) {
            #pragma unroll
            for (int j = 0; j < 8; ++j)
                bfr[g][h][j] = f2bf(Wr[(size_t)(h * 32 + kq * 8 + j) * 128 + g * 16 + c]);
        }
        rbias[g] = br[g * 16 + c];
    }

    int s_begin = wid * SEGS_PER_WAVE;
    for (int s = s_begin; s < s_begin + SEGS_PER_WAVE; ++s) {
        int base = off[s];
        int sz   = off[s + 1] - base;
        float sum[8];
        #pragma unroll
        for (int g = 0; g < 8; ++g) sum[g] = 0.f;

        int nb = (sz + 15) >> 4;
        for (int b = 0; b < nb; ++b) {
            bf16x8 a0 = {}, a1 = {};
            if (b * 16 + c < sz) {
                int node = ord[base + b * 16 + c];
                const float* xp = &x[(size_t)node * 64 + kq * 8];
                float4 v0 = *(const float4*)(xp);
                float4 v1 = *(const float4*)(xp + 4);
                float4 v2 = *(const float4*)(xp + 32);
                float4 v3 = *(const float4*)(xp + 36);
                a0[0] = f2bf(v0.x); a0[1] = f2bf(v0.y); a0[2] = f2bf(v0.z); a0[3] = f2bf(v0.w);
                a0[4] = f2bf(v1.x); a0[5] = f2bf(v1.y); a0[6] = f2bf(v1.z); a0[7] = f2bf(v1.w);
                a1[0] = f2bf(v2.x); a1[1] = f2bf(v2.y); a1[2] = f2bf(v2.z); a1[3] = f2bf(v2.w);
                a1[4] = f2bf(v3.x); a1[5] = f2bf(v3.y); a1[6] = f2bf(v3.z); a1[7] = f2bf(v3.w);
            }
            #pragma unroll
            for (int g = 0; g < 8; ++g) {
                f32x4 acc = {0.f, 0.f, 0.f, 0.f};
                acc = __builtin_amdgcn_mfma_f32_16x16x32_bf16(a0, bfr[g][0], acc, 0, 0, 0);
                acc = __builtin_amdgcn_mfma_f32_16x16x32_bf16(a1, bfr[g][1], acc, 0, 0, 0);
                #pragma unroll
                for (int r = 0; r < 4; ++r)
                    sum[g] += fmaxf(acc[r] + rbias[g], 0.f);   // relu BEFORE segment sum
            }
        }

        // reduce over row groups (C rows live on lane bits 4-5), fix padded rows, mean
        float padc = (float)(nb * 16 - sz);
        float inv  = (sz > 0) ? 1.f / (float)sz : 0.f;
        #pragma unroll
        for (int g = 0; g < 8; ++g) {
            float v = sum[g];
            v += __shfl_xor(v, 16);
            v += __shfl_xor(v, 32);
            v -= padc * fmaxf(rbias[g], 0.f);   // padded rows contributed relu(bias)
            sum[g] = v * inv;
        }
        // lane writes cols for groups 2*kq, 2*kq+1 at col c (each col exactly once)
        means[(size_t)s * 128 + (2 * kq + 0) * 16 + c] = sum[2 * kq + 0];
        means[(size_t)s * 128 + (2 * kq + 1) * 16 + c] = sum[2 * kq + 1];
    }
}

// ---------------- generic fp32 tiled GEMM: C = act(A[M,K] @ W[K,N] + bias) ----------------
template<int RELU>
__global__ __launch_bounds__(256) void gemm_kernel(
        const float* __restrict__ A, const float* __restrict__ W,
        const float* __restrict__ bias, float* __restrict__ C,
        int K, int ldc, int N) {
    __shared__ float As[16][68];
    __shared__ float Ws[16][64];
    int t  = threadIdx.x;
    int tx = t & 15, ty = t >> 4;
    int m0 = blockIdx.x * 64;
    int n0 = blockIdx.y * 64;

    float acc[4][4];
    #pragma unroll
    for (int j = 0; j < 4; ++j) {
        float bv = bias[n0 + tx * 4 + j];
        acc[0][j] = bv; acc[1][j] = bv; acc[2][j] = bv; acc[3][j] = bv;
    }

    int am = t >> 2, ak4 = t & 3;
    int wk = t >> 4, wn4 = t & 15;

    for (int k0 = 0; k0 < K; k0 += 16) {
        float4 av = *(const float4*)&A[(size_t)(m0 + am) * K + k0 + ak4 * 4];
        float4 wv = *(const float4*)&W[(size_t)(k0 + wk) * N + n0 + wn4 * 4];
        __syncthreads();
        As[ak4 * 4 + 0][am] = av.x;
        As[ak4 * 4 + 1][am] = av.y;
        As[ak4 * 4 + 2][am] = av.z;
        As[ak4 * 4 + 3][am] = av.w;
        *(float4*)&Ws[wk][wn4 * 4] = wv;
        __syncthreads();
        #pragma unroll
        for (int kk = 0; kk < 16; ++kk) {
            float4 a = *(const float4*)&As[kk][ty * 4];
            float4 w = *(const float4*)&Ws[kk][tx * 4];
            acc[0][0] = fmaf(a.x, w.x, acc[0][0]);
            acc[0][1] = fmaf(a.x, w.y, acc[0][1]);
            acc[0][2] = fmaf(a.x, w.z, acc[0][2]);
            acc[0][3] = fmaf(a.x, w.w, acc[0][3]);
            acc[1][0] = fmaf(a.y, w.x, acc[1][0]);
            acc[1][1] = fmaf(a.y, w.y, acc[1][1]);
            acc[1][2] = fmaf(a.y, w.z, acc[1][2]);
            acc[1][3] = fmaf(a.y, w.w, acc[1][3]);
            acc[2][0] = fmaf(a.z, w.x, acc[2][0]);
            acc[2][1] = fmaf(a.z, w.y, acc[2][1]);
            acc[2][2] = fmaf(a.z, w.z, acc[2][2]);
            acc[2][3] = fmaf(a.z, w.w, acc[2][3]);
            acc[3][0] = fmaf(a.w, w.x, acc[3][0]);
            acc[3][1] = fmaf(a.w, w.y, acc[3][1]);
            acc[3][2] = fmaf(a.w, w.z, acc[3][2]);
            acc[3][3] = fmaf(a.w, w.w, acc[3][3]);
        }
    }

    #pragma unroll
    for (int i = 0; i < 4; ++i) {
        float4 o;
        o.x = RELU ? fmaxf(acc[i][0], 0.f) : acc[i][0];
        o.y = RELU ? fmaxf(acc[i][1], 0.f) : acc[i][1];
        o.z = RELU ? fmaxf(acc[i][2], 0.f) : acc[i][2];
        o.w = RELU ? fmaxf(acc[i][3], 0.f) : acc[i][3];
        *(float4*)&C[(size_t)(m0 + ty * 4 + i) * ldc + n0 + tx * 4] = o;
    }
}

extern "C" void kernel_launch(void* const* d_in, const int* in_sizes, int n_in,
                              void* d_out, int out_size, void* d_ws, size_t ws_size,
                              hipStream_t stream) {
    const float* x0  = (const float*)d_in[0];
    const float* x1  = (const float*)d_in[1];
    const int*   idx0 = (const int*)d_in[2];
    const int*   idx1 = (const int*)d_in[3];
    const float* Wr0 = (const float*)d_in[4];
    const float* br0 = (const float*)d_in[5];
    const float* Wc0 = (const float*)d_in[6];
    const float* bc0 = (const float*)d_in[7];
    const float* Wr1 = (const float*)d_in[8];
    const float* br1 = (const float*)d_in[9];
    const float* Wc1 = (const float*)d_in[10];
    const float* bc1 = (const float*)d_in[11];
    const float* Wb1 = (const float*)d_in[12];
    const float* bb1 = (const float*)d_in[13];
    const float* Wb2 = (const float*)d_in[14];
    const float* bb2 = (const float*)d_in[15];
    float* out = (float*)d_out;

    const int N = N_NODES;
    char* w = (char*)d_ws;
    auto alloc = [&](size_t bytes) { void* p = (void*)w; w += (bytes + 255) & ~(size_t)255; return p; };
    int* cnt0 = (int*)alloc((size_t)B_SEG * 4);
    int* cnt1 = (int*)alloc((size_t)B_SEG * 4);
    int* off0 = (int*)alloc((size_t)(B_SEG + 1) * 4);
    int* off1 = (int*)alloc((size_t)(B_SEG + 1) * 4);
    int* ord0 = (int*)alloc((size_t)N * 4);
    int* ord1 = (int*)alloc((size_t)N * 4);
    float* means0 = (float*)alloc((size_t)B_SEG * 128 * 4);
    float* means1 = (float*)alloc((size_t)B_SEG * 128 * 4);
    float* z      = (float*)alloc((size_t)B_SEG * 256 * 4);
    float* hb     = means0;   // reuse means region as brain hidden buffer

    hipMemsetAsync(cnt0, 0, 2 * (size_t)B_SEG * sizeof(int), stream);
    histo_kernel<<<2048, 256, 0, stream>>>(idx0, idx1, cnt0, cnt1, N);
    scan_kernel<<<2, 1024, 0, stream>>>(cnt0, cnt1, off0, off1);
    fill_kernel<<<2048, 256, 0, stream>>>(idx0, idx1, off0, off1, cnt0, cnt1, ord0, ord1, N);

    // 2048 blocks * 4 waves * 8 segs = 65536 segments
    eye_means_mfma<<<2048, 256, 0, stream>>>(x0, Wr0, br0, off0, ord0, means0);
    eye_means_mfma<<<2048, 256, 0, stream>>>(x1, Wr1, br1, off1, ord1, means1);

    gemm_kernel<1><<<dim3(1024, 2), 256, 0, stream>>>(means0, Wc0, bc0, z,       128, 256, 128);
    gemm_kernel<1><<<dim3(1024, 2), 256, 0, stream>>>(means1, Wc1, bc1, z + 128, 128, 256, 128);
    gemm_kernel<1><<<dim3(1024, 4), 256, 0, stream>>>(z,  Wb1, bb1, hb,  256, 256, 256);
    gemm_kernel<0><<<dim3(1024, 2), 256, 0, stream>>>(hb, Wb2, bb2, out, 256, 128, 128);
}

// Round 4
// 507.010 us; speedup vs baseline: 3.4643x; 1.4931x over previous
//
#include <hip/hip_runtime.h>
#include <hip/hip_bf16.h>

#define B_SEG 65536
#define N_NODES 1048576

typedef _Float16 f16;
typedef __attribute__((ext_vector_type(8))) _Float16 f16x8;
typedef __attribute__((ext_vector_type(2))) __fp16 fp16x2;   // cvt_pkrtz's return type
typedef __attribute__((ext_vector_type(4))) float f32x4;

union F16x8 { f16x8 v; fp16x2 h2[4]; };

// ---------------- histogram, XCD-partitioned ----------------
// part = blockIdx&7 matches round-robin block->XCD mapping; each partition's
// 32KB counter slice is touched by one XCD's L2 only.
__global__ __launch_bounds__(256) void histo_part(const int* __restrict__ idx0,
        const int* __restrict__ idx1, int* __restrict__ cnt0, int* __restrict__ cnt1) {
    int part  = blockIdx.x & 7;
    int chunk = blockIdx.x >> 3;              // 0..255
    int base  = chunk * (N_NODES / 256);      // 4096 nodes per chunk
    for (int i = base + threadIdx.x; i < base + N_NODES / 256; i += 256) {
        int s0 = idx0[i];
        if ((s0 >> 13) == part) atomicAdd(&cnt0[s0], 1);
        int s1 = idx1[i];
        if ((s1 >> 13) == part) atomicAdd(&cnt1[s1], 1);
    }
}

// ---------------- 3-stage scan over 2x65536 counters ----------------
__global__ __launch_bounds__(256) void scan1(const int* __restrict__ cnt, int* __restrict__ bsum) {
    int b = blockIdx.x, t = threadIdx.x;
    int4 v = ((const int4*)cnt)[b * 256 + t];
    int s = v.x + v.y + v.z + v.w;
    for (int d = 1; d < 64; d <<= 1) s += __shfl_xor(s, d);
    __shared__ int ws4[4];
    if ((t & 63) == 0) ws4[t >> 6] = s;
    __syncthreads();
    if (t == 0) bsum[b] = ws4[0] + ws4[1] + ws4[2] + ws4[3];
}

// 128 threads = 2 waves; wave 0 scans eye0's 64 block sums, wave 1 eye1's.
__global__ __launch_bounds__(128) void scan2(int* __restrict__ bsum) {
    int t = threadIdx.x, lane = t & 63;
    int v = bsum[t];
    int s = v;
    for (int d = 1; d < 64; d <<= 1) { int u = __shfl_up(s, d); if (lane >= d) s += u; }
    bsum[t] = s - v;
}

__global__ __launch_bounds__(256) void scan3(int* __restrict__ cnt, const int* __restrict__ bsum,
                                             int* __restrict__ off0, int* __restrict__ off1) {
    int b = blockIdx.x, t = threadIdx.x;
    int4 v = ((const int4*)cnt)[b * 256 + t];
    int local = v.x + v.y + v.z + v.w;
    int lane = t & 63, w = t >> 6;
    int s = local;
    for (int d = 1; d < 64; d <<= 1) { int u = __shfl_up(s, d); if (lane >= d) s += u; }
    __shared__ int wsum[4];
    if (lane == 63) wsum[w] = s;
    __syncthreads();
    int carry = bsum[b];
    for (int i = 0; i < w; ++i) carry += wsum[i];
    int ex = carry + s - local;
    int* off = (b < 64) ? off0 : off1;
    int gi = (b & 63) * 1024 + t * 4;
    off[gi] = ex; ex += v.x; off[gi + 1] = ex; ex += v.y; off[gi + 2] = ex; ex += v.z; off[gi + 3] = ex;
    int4 z; z.x = 0; z.y = 0; z.z = 0; z.w = 0;
    ((int4*)cnt)[b * 256 + t] = z;            // reset counters for cursor reuse
    if (b == 0 && t == 0) { off0[B_SEG] = N_NODES; off1[B_SEG] = N_NODES; }
}

// ---------------- fill CSR, XCD-partitioned ----------------
__global__ __launch_bounds__(256) void fill_part(const int* __restrict__ idx0,
        const int* __restrict__ idx1, const int* __restrict__ off0, const int* __restrict__ off1,
        int* __restrict__ cur0, int* __restrict__ cur1,
        int* __restrict__ ord0, int* __restrict__ ord1) {
    int part  = blockIdx.x & 7;
    int chunk = blockIdx.x >> 3;
    int base  = chunk * (N_NODES / 256);
    for (int i = base + threadIdx.x; i < base + N_NODES / 256; i += 256) {
        int s0 = idx0[i];
        if ((s0 >> 13) == part) { int p = atomicAdd(&cur0[s0], 1); ord0[off0[s0] + p] = i; }
        int s1 = idx1[i];
        if ((s1 >> 13) == part) { int p = atomicAdd(&cur1[s1], 1); ord1[off1[s1] + p] = i; }
    }
}

// ---------------- weight transpose + f16 convert (one-time prep) ----------------
// BT layouts: T0,T1 = WcT [128][128]; T2 = Wb1T [256][256]; T3 = Wb2T [128][256]
__global__ __launch_bounds__(256) void prep_weights(
        const float* __restrict__ Wc0, const float* __restrict__ Wc1,
        const float* __restrict__ Wb1, const float* __restrict__ Wb2,
        f16* __restrict__ T0, f16* __restrict__ T1, f16* __restrict__ T2, f16* __restrict__ T3) {
    int b = blockIdx.x, t = threadIdx.x;
    if (b < 64)        { int i = b * 256 + t;         T0[i] = (f16)Wc0[(i & 127) * 128 + (i >> 7)]; }
    else if (b < 128)  { int i = (b - 64) * 256 + t;  T1[i] = (f16)Wc1[(i & 127) * 128 + (i >> 7)]; }
    else if (b < 384)  { int i = (b - 128) * 256 + t; T2[i] = (f16)Wb1[(i & 255) * 256 + (i >> 8)]; }
    else               { int i = (b - 384) * 256 + t; T3[i] = (f16)Wb2[(i & 255) * 128 + (i >> 8)]; }
}

// ---------------- per-segment mean of relu(x@Wr+br), f16 MFMA, pipelined ----------------
// One segment per wave. ord preloaded to a register (shfl for b<4), next batch's
// x rows prefetched during current batch's compute to hide the gather chain.
#define SEGS_PER_WAVE 8
__global__ __launch_bounds__(256, 3) void eye_means_mfma(
        const float* __restrict__ x, const float* __restrict__ Wr,
        const float* __restrict__ br, const int* __restrict__ off,
        const int* __restrict__ ord, f16* __restrict__ means) {
    int lane = threadIdx.x & 63;
    int wid  = blockIdx.x * 4 + (threadIdx.x >> 6);
    int c  = lane & 15;    // A row / C col within tile
    int kq = lane >> 4;    // k-quarter

    // B fragments: bfr[g][h] covers cols g*16..+15, k = h*32 + kq*8 .. +7
    f16x8 bfr[8][2];
    float rbias[8];
    #pragma unroll
    for (int g = 0; g < 8; ++g) {
        #pragma unroll
        for (int h = 0; h < 2; ++h)
            #pragma unroll
            for (int j = 0; j < 8; ++j)
                bfr[g][h][j] = (f16)Wr[(size_t)(h * 32 + kq * 8 + j) * 128 + g * 16 + c];
        rbias[g] = br[g * 16 + c];
    }

    int s_begin = wid * SEGS_PER_WAVE;
    for (int s = s_begin; s < s_begin + SEGS_PER_WAVE; ++s) {
        int base = off[s];
        int sz   = off[s + 1] - base;
        float sum[8];
        #pragma unroll
        for (int g = 0; g < 8; ++g) sum[g] = 0.f;
        int nb = (sz + 15) >> 4;

        if (nb > 0) {
            int ordv = ord[base + lane];            // ord padded +64 ints, safe
            float4 cv0, cv1, cv2, cv3;
            {
                int ni = c;
                int node = __shfl(ordv, ni);
                if (ni >= sz) node = 0;
                const float* xp = &x[(size_t)node * 64 + kq * 8];
                cv0 = *(const float4*)(xp);
                cv1 = *(const float4*)(xp + 4);
                cv2 = *(const float4*)(xp + 32);
                cv3 = *(const float4*)(xp + 36);
            }
            for (int b = 0; b < nb; ++b) {
                float4 nv0, nv1, nv2, nv3;
                if (b + 1 < nb) {                   // prefetch next batch (wave-uniform branch)
                    int ni = (b + 1) * 16 + c;
                    int node = (b + 1 < 4) ? __shfl(ordv, ni) : ord[base + ni];
                    if (ni >= sz) node = 0;
                    const float* xp = &x[(size_t)node * 64 + kq * 8];
                    nv0 = *(const float4*)(xp);
                    nv1 = *(const float4*)(xp + 4);
                    nv2 = *(const float4*)(xp + 32);
                    nv3 = *(const float4*)(xp + 36);
                }
                f16x8 a0 = {}, a1 = {};
                if (b * 16 + c < sz) {
                    F16x8 u0, u1;
                    u0.h2[0] = __builtin_amdgcn_cvt_pkrtz(cv0.x, cv0.y);
                    u0.h2[1] = __builtin_amdgcn_cvt_pkrtz(cv0.z, cv0.w);
                    u0.h2[2] = __builtin_amdgcn_cvt_pkrtz(cv1.x, cv1.y);
                    u0.h2[3] = __builtin_amdgcn_cvt_pkrtz(cv1.z, cv1.w);
                    u1.h2[0] = __builtin_amdgcn_cvt_pkrtz(cv2.x, cv2.y);
                    u1.h2[1] = __builtin_amdgcn_cvt_pkrtz(cv2.z, cv2.w);
                    u1.h2[2] = __builtin_amdgcn_cvt_pkrtz(cv3.x, cv3.y);
                    u1.h2[3] = __builtin_amdgcn_cvt_pkrtz(cv3.z, cv3.w);
                    a0 = u0.v; a1 = u1.v;
                }
                #pragma unroll
                for (int g = 0; g < 8; ++g) {
                    f32x4 acc = {0.f, 0.f, 0.f, 0.f};
                    acc = __builtin_amdgcn_mfma_f32_16x16x32_f16(a0, bfr[g][0], acc, 0, 0, 0);
                    acc = __builtin_amdgcn_mfma_f32_16x16x32_f16(a1, bfr[g][1], acc, 0, 0, 0);
                    #pragma unroll
                    for (int r = 0; r < 4; ++r)
                        sum[g] += fmaxf(acc[r] + rbias[g], 0.f);   // relu BEFORE segment sum
                }
                cv0 = nv0; cv1 = nv1; cv2 = nv2; cv3 = nv3;
            }
        }

        float padc = (float)(nb * 16 - sz);
        float inv  = (sz > 0) ? 1.f / (float)sz : 0.f;
        #pragma unroll
        for (int g = 0; g < 8; ++g) {
            float v = sum[g];
            v += __shfl_xor(v, 16);
            v += __shfl_xor(v, 32);
            v -= padc * fmaxf(rbias[g], 0.f);       // padded rows contributed relu(bias)
            sum[g] = v * inv;
        }
        means[(size_t)s * 128 + (2 * kq + 0) * 16 + c] = (f16)sum[2 * kq + 0];
        means[(size_t)s * 128 + (2 * kq + 1) * 16 + c] = (f16)sum[2 * kq + 1];
    }
}

// ---------------- f16 MFMA GEMM, zero-LDS: C = act(A[M,K] @ B + bias) ----------------
// BT is the f16-transposed weight [N][K]. A/B fragments loaded straight from
// global (16 rows x 64B contiguous per wave insn; B panel is L2-resident).
// Block = 4 waves x 32 rows = 128 rows; grid.y picks a 128-col panel.
template<int K, int RELU, int OUT16>
__global__ __launch_bounds__(256) void gemm16(
        const f16* __restrict__ A, const f16* __restrict__ BT,
        const float* __restrict__ bias, void* __restrict__ Cv, int ldc) {
    int lane = threadIdx.x & 63;
    int w = threadIdx.x >> 6;
    int c = lane & 15, kq = lane >> 4;
    int m0 = blockIdx.x * 128 + w * 32;
    int n0 = blockIdx.y * 128;

    f32x4 acc[2][8] = {};
    const f16* arow0 = A + (size_t)(m0 + c) * K + kq * 8;
    const f16* arow1 = arow0 + (size_t)16 * K;
    const f16* brow  = BT + (size_t)(n0 + c) * K + kq * 8;

    #pragma unroll 2
    for (int k0 = 0; k0 < K; k0 += 32) {
        f16x8 a0 = *(const f16x8*)(arow0 + k0);
        f16x8 a1 = *(const f16x8*)(arow1 + k0);
        #pragma unroll
        for (int g = 0; g < 8; ++g) {
            f16x8 bf = *(const f16x8*)(brow + (size_t)g * 16 * K + k0);
            acc[0][g] = __builtin_amdgcn_mfma_f32_16x16x32_f16(a0, bf, acc[0][g], 0, 0, 0);
            acc[1][g] = __builtin_amdgcn_mfma_f32_16x16x32_f16(a1, bf, acc[1][g], 0, 0, 0);
        }
    }

    #pragma unroll
    for (int g = 0; g < 8; ++g) {
        float bv = bias[n0 + g * 16 + c];
        #pragma unroll
        for (int ms = 0; ms < 2; ++ms) {
            #pragma unroll
            for (int r = 0; r < 4; ++r) {
                float v = acc[ms][g][r] + bv;
                if (RELU) v = fmaxf(v, 0.f);
                size_t ci = (size_t)(m0 + ms * 16 + kq * 4 + r) * ldc + n0 + g * 16 + c;
                if (OUT16) ((f16*)Cv)[ci] = (f16)v;
                else       ((float*)Cv)[ci] = v;
            }
        }
    }
}

extern "C" void kernel_launch(void* const* d_in, const int* in_sizes, int n_in,
                              void* d_out, int out_size, void* d_ws, size_t ws_size,
                              hipStream_t stream) {
    const float* x0  = (const float*)d_in[0];
    const float* x1  = (const float*)d_in[1];
    const int*   idx0 = (const int*)d_in[2];
    const int*   idx1 = (const int*)d_in[3];
    const float* Wr0 = (const float*)d_in[4];
    const float* br0 = (const float*)d_in[5];
    const float* Wc0 = (const float*)d_in[6];
    const float* bc0 = (const float*)d_in[7];
    const float* Wr1 = (const float*)d_in[8];
    const float* br1 = (const float*)d_in[9];
    const float* Wc1 = (const float*)d_in[10];
    const float* bc1 = (const float*)d_in[11];
    const float* Wb1 = (const float*)d_in[12];
    const float* bb1 = (const float*)d_in[13];
    const float* Wb2 = (const float*)d_in[14];
    const float* bb2 = (const float*)d_in[15];
    float* out = (float*)d_out;

    char* w = (char*)d_ws;
    auto alloc = [&](size_t bytes) { void* p = (void*)w; w += (bytes + 255) & ~(size_t)255; return p; };
    int* cnt0 = (int*)alloc((size_t)B_SEG * 4);              // 256KB -> cnt1 contiguous
    int* cnt1 = (int*)alloc((size_t)B_SEG * 4);
    int* off0 = (int*)alloc((size_t)(B_SEG + 1) * 4);
    int* off1 = (int*)alloc((size_t)(B_SEG + 1) * 4);
    int* ord0 = (int*)alloc((size_t)(N_NODES + 64) * 4);     // +64 pad for ordv preload
    int* ord1 = (int*)alloc((size_t)(N_NODES + 64) * 4);
    int* bsum = (int*)alloc(128 * 4);
    f16* means0 = (f16*)alloc((size_t)B_SEG * 128 * 2);
    f16* means1 = (f16*)alloc((size_t)B_SEG * 128 * 2);
    f16* z      = (f16*)alloc((size_t)B_SEG * 256 * 2);
    f16* hb     = (f16*)alloc((size_t)B_SEG * 256 * 2);
    f16* T0     = (f16*)alloc((size_t)128 * 128 * 2);
    f16* T1     = (f16*)alloc((size_t)128 * 128 * 2);
    f16* T2     = (f16*)alloc((size_t)256 * 256 * 2);
    f16* T3     = (f16*)alloc((size_t)128 * 256 * 2);

    (void)hipMemsetAsync(cnt0, 0, 2 * (size_t)B_SEG * sizeof(int), stream);
    histo_part<<<2048, 256, 0, stream>>>(idx0, idx1, cnt0, cnt1);
    scan1<<<128, 256, 0, stream>>>(cnt0, bsum);
    scan2<<<1, 128, 0, stream>>>(bsum);
    scan3<<<128, 256, 0, stream>>>(cnt0, bsum, off0, off1);
    fill_part<<<2048, 256, 0, stream>>>(idx0, idx1, off0, off1, cnt0, cnt1, ord0, ord1);
    prep_weights<<<512, 256, 0, stream>>>(Wc0, Wc1, Wb1, Wb2, T0, T1, T2, T3);

    eye_means_mfma<<<2048, 256, 0, stream>>>(x0, Wr0, br0, off0, ord0, means0);
    eye_means_mfma<<<2048, 256, 0, stream>>>(x1, Wr1, br1, off1, ord1, means1);

    gemm16<128, 1, 1><<<dim3(512, 1), 256, 0, stream>>>(means0, T0, bc0, z,       256);
    gemm16<128, 1, 1><<<dim3(512, 1), 256, 0, stream>>>(means1, T1, bc1, z + 128, 256);
    gemm16<256, 1, 1><<<dim3(512, 2), 256, 0, stream>>>(z,  T2, bb1, hb,  256);
    gemm16<256, 0, 0><<<dim3(512, 1), 256, 0, stream>>>(hb, T3, bb2, out, 128);
}

// Round 7
// 454.175 us; speedup vs baseline: 3.8673x; 1.1163x over previous
//
#include <hip/hip_runtime.h>
#include <hip/hip_bf16.h>

#define B_SEG 65536
#define N_NODES 1048576

typedef _Float16 f16;
typedef __attribute__((ext_vector_type(8))) _Float16 f16x8;
typedef __attribute__((ext_vector_type(2))) __fp16 fp16x2;   // cvt_pkrtz's return type
typedef __attribute__((ext_vector_type(4))) float f32x4;

union F16x8 { f16x8 v; fp16x2 h2[4]; };

// ---------------- histogram, XCD-partitioned ----------------
__global__ __launch_bounds__(256) void histo_part(const int* __restrict__ idx0,
        const int* __restrict__ idx1, int* __restrict__ cnt0, int* __restrict__ cnt1) {
    int part  = blockIdx.x & 7;
    int chunk = blockIdx.x >> 3;              // 0..255
    int base  = chunk * (N_NODES / 256);      // 4096 nodes per chunk
    for (int i = base + threadIdx.x; i < base + N_NODES / 256; i += 256) {
        int s0 = idx0[i];
        if ((s0 >> 13) == part) atomicAdd(&cnt0[s0], 1);
        int s1 = idx1[i];
        if ((s1 >> 13) == part) atomicAdd(&cnt1[s1], 1);
    }
}

// ---------------- 3-stage scan over 2x65536 counters ----------------
__global__ __launch_bounds__(256) void scan1(const int* __restrict__ cnt, int* __restrict__ bsum) {
    int b = blockIdx.x, t = threadIdx.x;
    int4 v = ((const int4*)cnt)[b * 256 + t];
    int s = v.x + v.y + v.z + v.w;
    for (int d = 1; d < 64; d <<= 1) s += __shfl_xor(s, d);
    __shared__ int ws4[4];
    if ((t & 63) == 0) ws4[t >> 6] = s;
    __syncthreads();
    if (t == 0) bsum[b] = ws4[0] + ws4[1] + ws4[2] + ws4[3];
}

__global__ __launch_bounds__(128) void scan2(int* __restrict__ bsum) {
    int t = threadIdx.x, lane = t & 63;
    int v = bsum[t];
    int s = v;
    for (int d = 1; d < 64; d <<= 1) { int u = __shfl_up(s, d); if (lane >= d) s += u; }
    bsum[t] = s - v;
}

__global__ __launch_bounds__(256) void scan3(int* __restrict__ cnt, const int* __restrict__ bsum,
                                             int* __restrict__ off0, int* __restrict__ off1) {
    int b = blockIdx.x, t = threadIdx.x;
    int4 v = ((const int4*)cnt)[b * 256 + t];
    int local = v.x + v.y + v.z + v.w;
    int lane = t & 63, w = t >> 6;
    int s = local;
    for (int d = 1; d < 64; d <<= 1) { int u = __shfl_up(s, d); if (lane >= d) s += u; }
    __shared__ int wsum[4];
    if (lane == 63) wsum[w] = s;
    __syncthreads();
    int carry = bsum[b];
    for (int i = 0; i < w; ++i) carry += wsum[i];
    int ex = carry + s - local;
    int* off = (b < 64) ? off0 : off1;
    int gi = (b & 63) * 1024 + t * 4;
    off[gi] = ex; ex += v.x; off[gi + 1] = ex; ex += v.y; off[gi + 2] = ex; ex += v.z; off[gi + 3] = ex;
    int4 z; z.x = 0; z.y = 0; z.z = 0; z.w = 0;
    ((int4*)cnt)[b * 256 + t] = z;            // reset counters for cursor reuse
    if (b == 0 && t == 0) { off0[B_SEG] = N_NODES; off1[B_SEG] = N_NODES; }
}

// ---------------- fill CSR, XCD-partitioned ----------------
__global__ __launch_bounds__(256) void fill_part(const int* __restrict__ idx0,
        const int* __restrict__ idx1, const int* __restrict__ off0, const int* __restrict__ off1,
        int* __restrict__ cur0, int* __restrict__ cur1,
        int* __restrict__ ord0, int* __restrict__ ord1) {
    int part  = blockIdx.x & 7;
    int chunk = blockIdx.x >> 3;
    int base  = chunk * (N_NODES / 256);
    for (int i = base + threadIdx.x; i < base + N_NODES / 256; i += 256) {
        int s0 = idx0[i];
        if ((s0 >> 13) == part) { int p = atomicAdd(&cur0[s0], 1); ord0[off0[s0] + p] = i; }
        int s1 = idx1[i];
        if ((s1 >> 13) == part) { int p = atomicAdd(&cur1[s1], 1); ord1[off1[s1] + p] = i; }
    }
}

// ---------------- weight transpose + f16 convert ----------------
__global__ __launch_bounds__(256) void prep_weights(
        const float* __restrict__ Wc0, const float* __restrict__ Wc1,
        const float* __restrict__ Wb1, const float* __restrict__ Wb2,
        f16* __restrict__ T0, f16* __restrict__ T1, f16* __restrict__ T2, f16* __restrict__ T3) {
    int b = blockIdx.x, t = threadIdx.x;
    if (b < 64)        { int i = b * 256 + t;         T0[i] = (f16)Wc0[(i & 127) * 128 + (i >> 7)]; }
    else if (b < 128)  { int i = (b - 64) * 256 + t;  T1[i] = (f16)Wc1[(i & 127) * 128 + (i >> 7)]; }
    else if (b < 384)  { int i = (b - 128) * 256 + t; T2[i] = (f16)Wb1[(i & 255) * 256 + (i >> 8)]; }
    else               { int i = (b - 384) * 256 + t; T3[i] = (f16)Wb2[(i & 255) * 128 + (i >> 8)]; }
}

// ---------------- per-segment mean of relu(x@Wr+br): nested-loop MFMA ----------------
// Round-4 control flow (nested per-segment loops, which passed) + three deltas:
//  (1) pooled ord preload: 3 lane-held regs = 192 entries, direct-load fallback;
//  (2) all shfls execute in UNIFORM flow (3 bpermutes + cndmask select, validity
//      select at the end) -- no shfl under divergent exec anywhere;
//  (3) cross-segment 1-deep x prefetch: a segment's last batch prefetches the
//      next segment's batch-0 rows. Empty segments (~1e-7) re-prime serially.
#define SEGS_PER_WAVE 8
__global__ __launch_bounds__(256, 3) void eye_means_mfma(
        const float* __restrict__ x, const float* __restrict__ Wr,
        const float* __restrict__ br, const int* __restrict__ off,
        const int* __restrict__ ord, f16* __restrict__ means) {
    int lane = threadIdx.x & 63;
    int wid  = blockIdx.x * 4 + (threadIdx.x >> 6);
    int c  = lane & 15;    // A row / C col within tile
    int kq = lane >> 4;    // k-quarter

    // B fragments: bfr[g][h] covers cols g*16..+15, k = h*32 + kq*8 .. +7
    f16x8 bfr[8][2];
    float rbias[8];
    #pragma unroll
    for (int g = 0; g < 8; ++g) {
        #pragma unroll
        for (int h = 0; h < 2; ++h)
            #pragma unroll
            for (int j = 0; j < 8; ++j)
                bfr[g][h][j] = (f16)Wr[(size_t)(h * 32 + kq * 8 + j) * 128 + g * 16 + c];
        rbias[g] = br[g * 16 + c];
    }

    int s_begin = wid * SEGS_PER_WAVE;
    int offv  = off[s_begin + ((lane <= 8) ? lane : 8)];     // lane i<=8: off[s_begin+i]
    int base0 = __shfl(offv, 0);
    int nxtv  = __shfl(offv, (lane < 8) ? (lane + 1) : 8);
    int szl   = nxtv - offv;             // lanes 0..7: size of segment i

    // pooled CSR preload: entries base0..base0+191 (mean 128, ~5.7 sigma)
    int ov0 = ord[base0 + lane];
    int ov1 = ord[base0 + 64 + lane];
    int ov2 = ord[base0 + 128 + lane];

    // node id for row r of segment at (off_rel, sz). Called ONLY in uniform flow;
    // all shfls full-exec; only the rare e>=192 fallback load is divergent.
    auto node_at = [&](int off_rel, int sz, int r) -> int {
        int e  = off_rel + r;
        int e6 = e & 63;
        int n0 = __shfl(ov0, e6);
        int n1 = __shfl(ov1, e6);
        int n2 = __shfl(ov2, e6);
        int n  = (e < 64) ? n0 : (e < 128) ? n1 : n2;
        if (e >= 192) n = ord[base0 + e];   // ord padded +256: always legal
        return (r < sz) ? n : 0;            // padded row -> node 0 (safe address)
    };

    auto loadx = [&](int node, float4& v0, float4& v1, float4& v2, float4& v3) {
        const float* xp = &x[(size_t)node * 64 + kq * 8];
        v0 = *(const float4*)(xp);      v1 = *(const float4*)(xp + 4);
        v2 = *(const float4*)(xp + 32); v3 = *(const float4*)(xp + 36);
    };

    float sum[8];
    #pragma unroll
    for (int g = 0; g < 8; ++g) sum[g] = 0.f;

    // prime pipeline with segment 0, batch 0
    float4 ca, cb, cc, cd;
    {
        int sz0 = __shfl(szl, 0);
        loadx(node_at(0, sz0, c), ca, cb, cc, cd);
    }

    #pragma unroll
    for (int s = 0; s < SEGS_PER_WAVE; ++s) {
        int off_rel   = __shfl(offv, s) - base0;
        int sz        = __shfl(szl, s);
        int nb        = (sz + 15) >> 4;
        int off_rel_n = (s < SEGS_PER_WAVE - 1) ? (__shfl(offv, s + 1) - base0) : 0;
        int sz_n      = (s < SEGS_PER_WAVE - 1) ? __shfl(szl, s + 1) : 0;
        size_t mb     = (size_t)(s_begin + s) * 128;

        if (nb == 0) {                       // empty segment: zero means, re-prime
            means[mb + (2 * kq + 0) * 16 + c] = (f16)0.f;
            means[mb + (2 * kq + 1) * 16 + c] = (f16)0.f;
            loadx(node_at(off_rel_n, sz_n, c), ca, cb, cc, cd);
            continue;
        }

        for (int b = 0; b < nb; ++b) {
            // prefetch next item: same-segment batch b+1, or next segment batch 0
            int nn = (b + 1 < nb) ? node_at(off_rel, sz, (b + 1) * 16 + c)
                                  : node_at(off_rel_n, sz_n, c);
            float4 pa, pb, pc, pd;
            loadx(nn, pa, pb, pc, pd);

            // compute current batch from ca..cd
            f16x8 A0 = {}, A1 = {};
            if (b * 16 + c < sz) {
                F16x8 u0, u1;
                u0.h2[0] = __builtin_amdgcn_cvt_pkrtz(ca.x, ca.y);
                u0.h2[1] = __builtin_amdgcn_cvt_pkrtz(ca.z, ca.w);
                u0.h2[2] = __builtin_amdgcn_cvt_pkrtz(cb.x, cb.y);
                u0.h2[3] = __builtin_amdgcn_cvt_pkrtz(cb.z, cb.w);
                u1.h2[0] = __builtin_amdgcn_cvt_pkrtz(cc.x, cc.y);
                u1.h2[1] = __builtin_amdgcn_cvt_pkrtz(cc.z, cc.w);
                u1.h2[2] = __builtin_amdgcn_cvt_pkrtz(cd.x, cd.y);
                u1.h2[3] = __builtin_amdgcn_cvt_pkrtz(cd.z, cd.w);
                A0 = u0.v; A1 = u1.v;
            }
            #pragma unroll
            for (int g = 0; g < 8; ++g) {
                f32x4 acc = {0.f, 0.f, 0.f, 0.f};
                acc = __builtin_amdgcn_mfma_f32_16x16x32_f16(A0, bfr[g][0], acc, 0, 0, 0);
                acc = __builtin_amdgcn_mfma_f32_16x16x32_f16(A1, bfr[g][1], acc, 0, 0, 0);
                #pragma unroll
                for (int r = 0; r < 4; ++r)
                    sum[g] += fmaxf(acc[r] + rbias[g], 0.f);   // relu BEFORE segment sum
            }
            ca = pa; cb = pb; cc = pc; cd = pd;
        }

        // flush segment s
        float padc = (float)(nb * 16 - sz);
        float inv  = 1.f / (float)sz;
        #pragma unroll
        for (int g = 0; g < 8; ++g) {
            float v = sum[g];
            v += __shfl_xor(v, 16);
            v += __shfl_xor(v, 32);
            v -= padc * fmaxf(rbias[g], 0.f);   // padded rows contributed relu(bias)
            sum[g] = v * inv;
        }
        means[mb + (2 * kq + 0) * 16 + c] = (f16)sum[2 * kq + 0];
        means[mb + (2 * kq + 1) * 16 + c] = (f16)sum[2 * kq + 1];
        #pragma unroll
        for (int g = 0; g < 8; ++g) sum[g] = 0.f;
    }
}

// ---------------- f16 MFMA GEMM, zero-LDS ----------------
template<int K, int RELU, int OUT16>
__global__ __launch_bounds__(256) void gemm16(
        const f16* __restrict__ A, const f16* __restrict__ BT,
        const float* __restrict__ bias, void* __restrict__ Cv, int ldc) {
    int lane = threadIdx.x & 63;
    int w = threadIdx.x >> 6;
    int c = lane & 15, kq = lane >> 4;
    int m0 = blockIdx.x * 128 + w * 32;
    int n0 = blockIdx.y * 128;

    f32x4 acc[2][8] = {};
    const f16* arow0 = A + (size_t)(m0 + c) * K + kq * 8;
    const f16* arow1 = arow0 + (size_t)16 * K;
    const f16* brow  = BT + (size_t)(n0 + c) * K + kq * 8;

    #pragma unroll 2
    for (int k0 = 0; k0 < K; k0 += 32) {
        f16x8 a0 = *(const f16x8*)(arow0 + k0);
        f16x8 a1 = *(const f16x8*)(arow1 + k0);
        #pragma unroll
        for (int g = 0; g < 8; ++g) {
            f16x8 bf = *(const f16x8*)(brow + (size_t)g * 16 * K + k0);
            acc[0][g] = __builtin_amdgcn_mfma_f32_16x16x32_f16(a0, bf, acc[0][g], 0, 0, 0);
            acc[1][g] = __builtin_amdgcn_mfma_f32_16x16x32_f16(a1, bf, acc[1][g], 0, 0, 0);
        }
    }

    #pragma unroll
    for (int g = 0; g < 8; ++g) {
        float bv = bias[n0 + g * 16 + c];
        #pragma unroll
        for (int ms = 0; ms < 2; ++ms) {
            #pragma unroll
            for (int r = 0; r < 4; ++r) {
                float v = acc[ms][g][r] + bv;
                if (RELU) v = fmaxf(v, 0.f);
                size_t ci = (size_t)(m0 + ms * 16 + kq * 4 + r) * ldc + n0 + g * 16 + c;
                if (OUT16) ((f16*)Cv)[ci] = (f16)v;
                else       ((float*)Cv)[ci] = v;
            }
        }
    }
}

extern "C" void kernel_launch(void* const* d_in, const int* in_sizes, int n_in,
                              void* d_out, int out_size, void* d_ws, size_t ws_size,
                              hipStream_t stream) {
    const float* x0  = (const float*)d_in[0];
    const float* x1  = (const float*)d_in[1];
    const int*   idx0 = (const int*)d_in[2];
    const int*   idx1 = (const int*)d_in[3];
    const float* Wr0 = (const float*)d_in[4];
    const float* br0 = (const float*)d_in[5];
    const float* Wc0 = (const float*)d_in[6];
    const float* bc0 = (const float*)d_in[7];
    const float* Wr1 = (const float*)d_in[8];
    const float* br1 = (const float*)d_in[9];
    const float* Wc1 = (const float*)d_in[10];
    const float* bc1 = (const float*)d_in[11];
    const float* Wb1 = (const float*)d_in[12];
    const float* bb1 = (const float*)d_in[13];
    const float* Wb2 = (const float*)d_in[14];
    const float* bb2 = (const float*)d_in[15];
    float* out = (float*)d_out;

    char* w = (char*)d_ws;
    auto alloc = [&](size_t bytes) { void* p = (void*)w; w += (bytes + 255) & ~(size_t)255; return p; };
    int* cnt0 = (int*)alloc((size_t)B_SEG * 4);
    int* cnt1 = (int*)alloc((size_t)B_SEG * 4);
    int* off0 = (int*)alloc((size_t)(B_SEG + 1) * 4);
    int* off1 = (int*)alloc((size_t)(B_SEG + 1) * 4);
    int* ord0 = (int*)alloc((size_t)(N_NODES + 256) * 4);    // +256 pad: pooled preload
    int* ord1 = (int*)alloc((size_t)(N_NODES + 256) * 4);
    int* bsum = (int*)alloc(128 * 4);
    f16* means0 = (f16*)alloc((size_t)B_SEG * 128 * 2);
    f16* means1 = (f16*)alloc((size_t)B_SEG * 128 * 2);
    f16* z      = (f16*)alloc((size_t)B_SEG * 256 * 2);
    f16* hb     = (f16*)alloc((size_t)B_SEG * 256 * 2);
    f16* T0     = (f16*)alloc((size_t)128 * 128 * 2);
    f16* T1     = (f16*)alloc((size_t)128 * 128 * 2);
    f16* T2     = (f16*)alloc((size_t)256 * 256 * 2);
    f16* T3     = (f16*)alloc((size_t)128 * 256 * 2);

    (void)hipMemsetAsync(cnt0, 0, 2 * (size_t)B_SEG * sizeof(int), stream);
    histo_part<<<2048, 256, 0, stream>>>(idx0, idx1, cnt0, cnt1);
    scan1<<<128, 256, 0, stream>>>(cnt0, bsum);
    scan2<<<1, 128, 0, stream>>>(bsum);
    scan3<<<128, 256, 0, stream>>>(cnt0, bsum, off0, off1);
    fill_part<<<2048, 256, 0, stream>>>(idx0, idx1, off0, off1, cnt0, cnt1, ord0, ord1);
    prep_weights<<<512, 256, 0, stream>>>(Wc0, Wc1, Wb1, Wb2, T0, T1, T2, T3);

    // 2048 blocks x 4 waves x 8 segs = 65536 segments per eye
    eye_means_mfma<<<2048, 256, 0, stream>>>(x0, Wr0, br0, off0, ord0, means0);
    eye_means_mfma<<<2048, 256, 0, stream>>>(x1, Wr1, br1, off1, ord1, means1);

    gemm16<128, 1, 1><<<dim3(512, 1), 256, 0, stream>>>(means0, T0, bc0, z,       256);
    gemm16<128, 1, 1><<<dim3(512, 1), 256, 0, stream>>>(means1, T1, bc1, z + 128, 256);
    gemm16<256, 1, 1><<<dim3(512, 2), 256, 0, stream>>>(z,  T2, bb1, hb,  256);
    gemm16<256, 0, 0><<<dim3(512, 1), 256, 0, stream>>>(hb, T3, bb2, out, 128);
}